// Round 1
// 4021.794 us; speedup vs baseline: 6.0142x; 6.0142x over previous
//
#include <hip/hip_runtime.h>

// SGEncoder — round 1: MFMA-ized fused MLPs (bf16, hi/lo-split layer-1 activations).
// Pipeline:
//   0. pack 6 weight matrices -> fragment-major bf16 in ws (per launch, tiny)
//   1. memset(agg, cnt, graph stats) = 0
//   2. sign[E] = 1, sign[added_sym_edge] = -1
//   3. x[N][300]  = sum_t emb[x_tok]; ea[E][300] = sign * sum_t emb[ea_tok]
//   4. edge MLP  (Fin=900) MFMA -> edge_enc, in-place over ea
//   5. cnt[col] += 1
//   6. node MLP1 (Fin=600) MFMA -> atomicAdd into agg[col]   (atomics kept fp32 this round)
//   7. node MLP2 (Fin=600) MFMA -> x_enc into d_out[0:N*D]
//   8-9. graph layernorm
//
// MFMA geometry: 16x16x32 bf16. Block = 64 rows x 320 cols (300 + pad), 4 waves,
// wave w owns cols [80w, 80w+80) = 5 n-tiles, 4 m-tiles, K staged in 64-chunks.
// Layer-1 A is split hi+lo bf16 (2 MFMAs) -> activation rounding ~2^-17;
// hidden stays single bf16 (same precision as previous passing kernel).

constexpr int N_NODES = 100000;
constexpr int N_EDGES = 400000;
constexpr int TOKS    = 4;
constexpr int D       = 300;
constexpr int NG      = 128;
constexpr float EPSV  = 1e-5f;

typedef __attribute__((ext_vector_type(8))) short bh8;
typedef __attribute__((ext_vector_type(4))) float fx4;

// ---- workspace layout (float elements) ----
constexpr size_t AGG_OFF  = 0;                                // N*D
constexpr size_t CNT_OFF  = AGG_OFF + (size_t)N_NODES * D;    // N
constexpr size_t GSUM_OFF = CNT_OFF + N_NODES;                // G
constexpr size_t GSQ_OFF  = GSUM_OFF + NG;                    // G
constexpr size_t GCNT_OFF = GSQ_OFF + NG;                     // G
constexpr size_t SIGN_OFF = GCNT_OFF + NG;                    // E
constexpr size_t X_OFF    = SIGN_OFF + N_EDGES;               // N*D
constexpr size_t PACK_OFF = X_OFF + (size_t)N_NODES * D;      // packed weights (ushort)
constexpr size_t ZERO_FLOATS = SIGN_OFF;                      // [0, SIGN_OFF) zeroed

// packed weight sizes in ushorts: KT*20*64*8, KT = secs*10
constexpr size_t P_SEC3 = 30ull * 20 * 64 * 8;   // 307200 (Fin=900)
constexpr size_t P_SEC2 = 20ull * 20 * 64 * 8;   // 204800 (Fin=600)
constexpr size_t P_SEC1 = 10ull * 20 * 64 * 8;   // 102400 (Fin=300)

__device__ inline unsigned short f2bf(float f) {     // fp32 -> bf16 RNE
    unsigned int u = __float_as_uint(f);
    return (unsigned short)((u + 0x7fffu + ((u >> 16) & 1u)) >> 16);
}
__device__ inline float bf2f(unsigned short s) {
    return __uint_as_float(((unsigned int)s) << 16);
}

__global__ void fill_sign_k(float* sign) {
    int i = blockIdx.x * blockDim.x + threadIdx.x;
    if (i < N_EDGES) sign[i] = 1.0f;
}

__global__ void scatter_sign_k(const int* __restrict__ ase, float* sign) {
    int i = blockIdx.x * blockDim.x + threadIdx.x;
    if (i < N_EDGES / 2) sign[ase[i]] = -1.0f;
}

// out[r][d] = (sign ? sign[r] : 1) * sum_t emb[tok[r][t]][d]
__global__ void embsum_k(const int* __restrict__ tok, const float* __restrict__ emb,
                         const float* __restrict__ sign, float* out, int nrows) {
    int idx = blockIdx.x * blockDim.x + threadIdx.x;
    int total = nrows * D;
    if (idx >= total) return;
    int r = idx / D;
    int d = idx - r * D;
    const int* t = tok + r * TOKS;
    float s = emb[(size_t)t[0] * D + d] + emb[(size_t)t[1] * D + d]
            + emb[(size_t)t[2] * D + d] + emb[(size_t)t[3] * D + d];
    if (sign) s *= sign[r];
    out[idx] = s;
}

__global__ void count_col_k(const int* __restrict__ coli, float* cnt) {
    int i = blockIdx.x * blockDim.x + threadIdx.x;
    if (i < N_EDGES) atomicAdd(&cnt[coli[i]], 1.0f);
}

// Pack W [secs*300][300] fp32 -> fragment-major bf16 [kt][nt(20)][lane(64)][8].
// Fragment: lane holds B[k = kt*32 + (lane>>4)*8 + j][col = nt*16 + (lane&15)].
// K padded per 300-section to 320; pads (kk>=300 or col>=300) are zero.
__global__ void pack_w_k(const float* __restrict__ W, unsigned short* __restrict__ out,
                         int secs) {
    int idx = blockIdx.x * blockDim.x + threadIdx.x;
    int total = secs * 12800;                 // (secs*10) kt * 20 nt * 64 lanes
    if (idx >= total) return;
    int lane = idx & 63;
    int nt = (idx >> 6) % 20;
    int kt = idx / 1280;
    int col = nt * 16 + (lane & 15);
    int kg = (lane >> 4) * 8;
#pragma unroll
    for (int j = 0; j < 8; ++j) {
        int p = kt * 32 + kg + j;
        int sec = p / 320;
        int kk = p - sec * 320;
        float w = 0.f;
        if (kk < 300 && col < 300) w = W[(size_t)(sec * 300 + kk) * 300 + col];
        out[(size_t)idx * 8 + j] = f2bf(w);
    }
}

// Fused 2-layer MLP on MFMA. SECS = Fin/300.
// MODE 0: A = [x[row], x[col], ea[e]]   (edge MLP), store outp (== aux in-place ok)
// MODE 1: A = [x[row], edge_enc[e]],    SCATTER: atomicAdd outp[col[e]]
// MODE 2: A = [x[n], agg[n]/cnt[n]],    store outp
template <int SECS, int MODE, bool SCATTER>
__global__ __launch_bounds__(256, 2) void mlp_mfma_k(
        const float* __restrict__ x, const float* aux,
        const int* __restrict__ rowi, const int* __restrict__ coli,
        const float* __restrict__ cnt,
        const unsigned short* __restrict__ W1p, const float* __restrict__ b1,
        const unsigned short* __restrict__ W2p, const float* __restrict__ b2,
        float* outp, int nrows)
{
    constexpr int NCHUNK = SECS * 5;   // 64-wide K chunks in padded layer-1 K
    __shared__ __align__(16) unsigned short Ahi[4096];   // [kt2][mt4][lane64][8]
    __shared__ __align__(16) unsigned short Alo[4096];
    __shared__ __align__(16) unsigned short Hs[64 * 328]; // hidden bf16, stride 328
    __shared__ int Ridx[64];
    __shared__ int Cidx[64];
    __shared__ float Icnt[64];

    const int tid  = threadIdx.x;
    const int wave = tid >> 6;
    const int lane = tid & 63;
    const int r0   = blockIdx.x * 64;

    if (tid < 64) {
        int e = r0 + tid; if (e >= nrows) e = nrows - 1;
        if constexpr (MODE == 0 || MODE == 1) { Ridx[tid] = rowi[e]; Cidx[tid] = coli[e]; }
        else { Icnt[tid] = 1.0f / fmaxf(cnt[e], 1.0f); }
    }
    // zero hidden pad cols [300,320) so layer-2 pad fragments are clean
    for (int i = tid; i < 64 * 20; i += 256)
        Hs[(i / 20) * 328 + 300 + (i % 20)] = 0;
    __syncthreads();

    // staging geometry: thread -> (row sm, 16-float run at sko within chunk)
    const int sm  = tid >> 2;
    const int sko = (tid & 3) << 4;
    const int skt   = sko >> 5;
    const int sg0   = (sko & 31) >> 3;
    const int smt   = sm >> 4;
    const int sbase = ((skt * 4 + smt) * 64 + (sm & 15) + sg0 * 16) * 8;
    int se = r0 + sm; if (se >= nrows) se = nrows - 1;

    fx4 acc[4][5];
#pragma unroll
    for (int a = 0; a < 4; ++a)
#pragma unroll
        for (int b = 0; b < 5; ++b) acc[a][b] = fx4{0.f, 0.f, 0.f, 0.f};

    // ---------------- layer 1: acc = A @ W1 (A split hi/lo bf16) ----------------
    for (int c = 0; c < NCHUNK; ++c) {
        {   // stage chunk c: each thread converts 16 floats -> 2x(hi,lo) bh8
            int sec = (c * 64) / 320;               // chunks never cross sections
            int kk0 = c * 64 - sec * 320 + sko;     // within-section k
            const float* base;
            if constexpr (MODE == 0) {
                base = (sec == 0) ? x + (size_t)Ridx[sm] * 300
                     : (sec == 1) ? x + (size_t)Cidx[sm] * 300
                                  : aux + (size_t)se * 300;
            } else if constexpr (MODE == 1) {
                base = (sec == 0) ? x + (size_t)Ridx[sm] * 300
                                  : aux + (size_t)se * 300;
            } else {
                base = (sec == 0) ? x + (size_t)se * 300 : aux + (size_t)se * 300;
            }
            float f[16];
            if (kk0 + 16 <= 300) {
                const float4* p = (const float4*)(base + kk0);
                float4 q0 = p[0], q1 = p[1], q2 = p[2], q3 = p[3];
                f[0]=q0.x; f[1]=q0.y; f[2]=q0.z; f[3]=q0.w;
                f[4]=q1.x; f[5]=q1.y; f[6]=q1.z; f[7]=q1.w;
                f[8]=q2.x; f[9]=q2.y; f[10]=q2.z; f[11]=q2.w;
                f[12]=q3.x; f[13]=q3.y; f[14]=q3.z; f[15]=q3.w;
            } else {
#pragma unroll
                for (int i = 0; i < 16; ++i) {
                    int kk = kk0 + i;
                    f[i] = (kk < 300) ? base[kk] : 0.f;
                }
            }
            if constexpr (MODE == 2) {
                float scale = (sec == 1) ? Icnt[sm] : 1.0f;
#pragma unroll
                for (int i = 0; i < 16; ++i) f[i] *= scale;
            }
            bh8 vh0, vl0, vh1, vl1;
#pragma unroll
            for (int i = 0; i < 8; ++i) {
                unsigned short h0 = f2bf(f[i]);
                vh0[i] = (short)h0;
                vl0[i] = (short)f2bf(f[i] - bf2f(h0));
                unsigned short h1 = f2bf(f[8 + i]);
                vh1[i] = (short)h1;
                vl1[i] = (short)f2bf(f[8 + i] - bf2f(h1));
            }
            *(bh8*)&Ahi[sbase]       = vh0;
            *(bh8*)&Ahi[sbase + 128] = vh1;
            *(bh8*)&Alo[sbase]       = vl0;
            *(bh8*)&Alo[sbase + 128] = vl1;
        }
        __syncthreads();
#pragma unroll
        for (int kt = 0; kt < 2; ++kt) {
            const int ktg = c * 2 + kt;
            bh8 bfr[5];
#pragma unroll
            for (int nt = 0; nt < 5; ++nt)
                bfr[nt] = *(const bh8*)(W1p + (((size_t)ktg * 20 + wave * 5 + nt) * 64 + lane) * 8);
#pragma unroll
            for (int mt = 0; mt < 4; ++mt) {
                bh8 ah = *(const bh8*)&Ahi[((kt * 4 + mt) * 64 + lane) * 8];
                bh8 al = *(const bh8*)&Alo[((kt * 4 + mt) * 64 + lane) * 8];
#pragma unroll
                for (int nt = 0; nt < 5; ++nt) {
                    acc[mt][nt] = __builtin_amdgcn_mfma_f32_16x16x32_bf16(ah, bfr[nt], acc[mt][nt], 0, 0, 0);
                    acc[mt][nt] = __builtin_amdgcn_mfma_f32_16x16x32_bf16(al, bfr[nt], acc[mt][nt], 0, 0, 0);
                }
            }
        }
        __syncthreads();
    }

    // epilogue 1: Hs = bf16(relu(acc + b1)); D-frag: col=lane&15, row=(lane>>4)*4+r
    {
        const int rg = (lane >> 4) * 4;
#pragma unroll
        for (int nt = 0; nt < 5; ++nt) {
            int col = (wave * 5 + nt) * 16 + (lane & 15);
            if (col < 300) {
                float bb = b1[col];
#pragma unroll
                for (int mt = 0; mt < 4; ++mt)
#pragma unroll
                    for (int r = 0; r < 4; ++r) {
                        float v = fmaxf(acc[mt][nt][r] + bb, 0.f);
                        Hs[(mt * 16 + rg + r) * 328 + col] = f2bf(v);
                    }
            }
        }
    }
    __syncthreads();

    // ---------------- layer 2: acc2 = Hs @ W2 (single bf16) ----------------
    fx4 acc2[4][5];
#pragma unroll
    for (int a = 0; a < 4; ++a)
#pragma unroll
        for (int b = 0; b < 5; ++b) acc2[a][b] = fx4{0.f, 0.f, 0.f, 0.f};

    for (int kt = 0; kt < 10; ++kt) {
        bh8 bfr[5];
#pragma unroll
        for (int nt = 0; nt < 5; ++nt)
            bfr[nt] = *(const bh8*)(W2p + (((size_t)kt * 20 + wave * 5 + nt) * 64 + lane) * 8);
#pragma unroll
        for (int mt = 0; mt < 4; ++mt) {
            bh8 ah = *(const bh8*)&Hs[(mt * 16 + (lane & 15)) * 328 + kt * 32 + (lane >> 4) * 8];
#pragma unroll
            for (int nt = 0; nt < 5; ++nt)
                acc2[mt][nt] = __builtin_amdgcn_mfma_f32_16x16x32_bf16(ah, bfr[nt], acc2[mt][nt], 0, 0, 0);
        }
    }

    // epilogue 2: store / scatter
    {
        const int rg = (lane >> 4) * 4;
#pragma unroll
        for (int nt = 0; nt < 5; ++nt) {
            int col = (wave * 5 + nt) * 16 + (lane & 15);
            if (col >= 300) continue;
            float bb = b2[col];
#pragma unroll
            for (int mt = 0; mt < 4; ++mt)
#pragma unroll
                for (int r = 0; r < 4; ++r) {
                    int m = mt * 16 + rg + r;
                    int e = r0 + m;
                    if (e >= nrows) continue;
                    float v = acc2[mt][nt][r] + bb;
                    if constexpr (SCATTER) atomicAdd(&outp[(size_t)Cidx[m] * 300 + col], v);
                    else                   outp[(size_t)e * 300 + col] = v;
                }
        }
    }
}

// one block per node: partial sums -> per-graph atomics
__global__ __launch_bounds__(256) void graph_stats_k(
        const float* __restrict__ xe, const int* __restrict__ batch,
        float* gsum, float* gsq, float* gcnt) {
    int n = blockIdx.x;
    int tid = threadIdx.x;
    float v = 0.f, v2 = 0.f;
    for (int d = tid; d < D; d += 256) {
        float t = xe[(size_t)n * D + d];
        v += t; v2 += t * t;
    }
    for (int off = 32; off > 0; off >>= 1) {
        v  += __shfl_down(v, off, 64);
        v2 += __shfl_down(v2, off, 64);
    }
    __shared__ float s1[4], s2[4];
    int w = tid >> 6, l = tid & 63;
    if (l == 0) { s1[w] = v; s2[w] = v2; }
    __syncthreads();
    if (tid == 0) {
        float a = s1[0] + s1[1] + s1[2] + s1[3];
        float b = s2[0] + s2[1] + s2[2] + s2[3];
        int g = batch[n];
        atomicAdd(&gsum[g], a);
        atomicAdd(&gsq[g], b);
        atomicAdd(&gcnt[g], 1.0f);
    }
}

__global__ void graph_norm_k(float* xe, const int* __restrict__ batch,
                             const float* __restrict__ gsum, const float* __restrict__ gsq,
                             const float* __restrict__ gcnt,
                             const float* __restrict__ lnw, const float* __restrict__ lnb) {
    int idx = blockIdx.x * blockDim.x + threadIdx.x;
    if (idx >= N_NODES * D) return;
    int n = idx / D;
    int d = idx - n * D;
    int g = batch[n];
    float denom = fmaxf(gcnt[g] * (float)D, 1.0f);
    float mean = gsum[g] / denom;
    float var  = gsq[g] / denom - mean * mean;
    float r = rsqrtf(var + EPSV);
    xe[idx] = (xe[idx] - mean) * r * lnw[d] + lnb[d];
}

extern "C" void kernel_launch(void* const* d_in, const int* in_sizes, int n_in,
                              void* d_out, int out_size, void* d_ws, size_t ws_size,
                              hipStream_t stream) {
    const int*   x_tok  = (const int*)d_in[0];
    const int*   ea_tok = (const int*)d_in[1];
    const int*   eidx   = (const int*)d_in[2];
    const int*   ase    = (const int*)d_in[3];
    const int*   batch  = (const int*)d_in[4];
    const float* emb    = (const float*)d_in[5];
    const float* ew1  = (const float*)d_in[6];
    const float* eb1  = (const float*)d_in[7];
    const float* ew2  = (const float*)d_in[8];
    const float* eb2  = (const float*)d_in[9];
    const float* n1w1 = (const float*)d_in[10];
    const float* n1b1 = (const float*)d_in[11];
    const float* n1w2 = (const float*)d_in[12];
    const float* n1b2 = (const float*)d_in[13];
    const float* n2w1 = (const float*)d_in[14];
    const float* n2b1 = (const float*)d_in[15];
    const float* n2w2 = (const float*)d_in[16];
    const float* n2b2 = (const float*)d_in[17];
    const float* lnw  = (const float*)d_in[18];
    const float* lnb  = (const float*)d_in[19];

    const int* rowi = eidx;
    const int* coli = eidx + N_EDGES;

    float* out  = (float*)d_out;
    float* xout = out;
    float* eenc = out + (size_t)N_NODES * D;

    float* ws   = (float*)d_ws;
    float* agg  = ws + AGG_OFF;
    float* cnt  = ws + CNT_OFF;
    float* gsum = ws + GSUM_OFF;
    float* gsq  = ws + GSQ_OFF;
    float* gcnt = ws + GCNT_OFF;
    float* sign = ws + SIGN_OFF;
    float* x    = ws + X_OFF;

    unsigned short* ew1p  = (unsigned short*)(ws + PACK_OFF);
    unsigned short* ew2p  = ew1p  + P_SEC3;
    unsigned short* n1w1p = ew2p  + P_SEC1;
    unsigned short* n1w2p = n1w1p + P_SEC2;
    unsigned short* n2w1p = n1w2p + P_SEC1;
    unsigned short* n2w2p = n2w1p + P_SEC2;

    // 0. pack weights to fragment-major bf16
    pack_w_k<<<(3 * 12800 + 255) / 256, 256, 0, stream>>>(ew1,  ew1p,  3);
    pack_w_k<<<(1 * 12800 + 255) / 256, 256, 0, stream>>>(ew2,  ew2p,  1);
    pack_w_k<<<(2 * 12800 + 255) / 256, 256, 0, stream>>>(n1w1, n1w1p, 2);
    pack_w_k<<<(1 * 12800 + 255) / 256, 256, 0, stream>>>(n1w2, n1w2p, 1);
    pack_w_k<<<(2 * 12800 + 255) / 256, 256, 0, stream>>>(n2w1, n2w1p, 2);
    pack_w_k<<<(1 * 12800 + 255) / 256, 256, 0, stream>>>(n2w2, n2w2p, 1);

    // 1. zero accumulators
    hipMemsetAsync(ws, 0, ZERO_FLOATS * sizeof(float), stream);

    // 2. sign
    fill_sign_k<<<(N_EDGES + 255) / 256, 256, 0, stream>>>(sign);
    scatter_sign_k<<<(N_EDGES / 2 + 255) / 256, 256, 0, stream>>>(ase, sign);

    // 3. embedding sums
    embsum_k<<<(N_NODES * D + 255) / 256, 256, 0, stream>>>(x_tok, emb, nullptr, x, N_NODES);
    embsum_k<<<(N_EDGES * D + 255) / 256, 256, 0, stream>>>(ea_tok, emb, sign, eenc, N_EDGES);

    // 4. edge MLP (in-place over ea in d_out)
    mlp_mfma_k<3, 0, false><<<N_EDGES / 64, 256, 0, stream>>>(
        x, eenc, rowi, coli, nullptr, ew1p, eb1, ew2p, eb2, eenc, N_EDGES);

    // 5. in-degree counts
    count_col_k<<<(N_EDGES + 255) / 256, 256, 0, stream>>>(coli, cnt);

    // 6. node MLP1 -> scatter-add into agg
    mlp_mfma_k<2, 1, true><<<N_EDGES / 64, 256, 0, stream>>>(
        x, eenc, rowi, coli, nullptr, n1w1p, n1b1, n1w2p, n1b2, agg, N_EDGES);

    // 7. node MLP2 (agg/cnt folded into gather) -> x_enc in d_out
    mlp_mfma_k<2, 2, false><<<(N_NODES + 63) / 64, 256, 0, stream>>>(
        x, agg, nullptr, nullptr, cnt, n2w1p, n2b1, n2w2p, n2b2, xout, N_NODES);

    // 8-9. graph layernorm
    graph_stats_k<<<N_NODES, 256, 0, stream>>>(xout, batch, gsum, gsq, gcnt);
    graph_norm_k<<<(N_NODES * D + 255) / 256, 256, 0, stream>>>(
        xout, batch, gsum, gsq, gcnt, lnw, lnb);
}

// Round 3
// 3631.074 us; speedup vs baseline: 6.6613x; 1.1076x over previous
//
#include <hip/hip_runtime.h>

// SGEncoder — round 3: round-2 design, de-risked.
//  - LDS union: Abuf (layer-1 staging, 32KB) and Hs (hidden, 40KB) share one 40KB
//    region (Abuf dead after last layer-1 MFMA; barrier-separated) -> 41KB total.
//  - standard __syncthreads() only; prefetch restructured to issue gather loads at
//    the TOP of each iteration (consumed after the MFMA phase) so the barrier's
//    vmcnt drain is free.
//  - fused ea embedding-sum in edge MLP; perm-packed exact hi/lo bf16 split;
//    fragment-major Hs; graph stats fused into node-MLP2; float4 embsum/norm.

constexpr int N_NODES = 100000;
constexpr int N_EDGES = 400000;
constexpr int D       = 300;
constexpr int NG      = 128;
constexpr float EPSV  = 1e-5f;

typedef __attribute__((ext_vector_type(8))) short bh8;
typedef __attribute__((ext_vector_type(4))) float fx4;

// ---- workspace layout (float elements) ----
constexpr size_t AGG_OFF  = 0;                                // N*D
constexpr size_t CNT_OFF  = AGG_OFF + (size_t)N_NODES * D;    // N
constexpr size_t GSUM_OFF = CNT_OFF + N_NODES;                // G
constexpr size_t GSQ_OFF  = GSUM_OFF + NG;                    // G
constexpr size_t GCNT_OFF = GSQ_OFF + NG;                     // G
constexpr size_t SIGN_OFF = GCNT_OFF + NG;                    // E
constexpr size_t X_OFF    = SIGN_OFF + N_EDGES;               // N*D
constexpr size_t PACK_OFF = X_OFF + (size_t)N_NODES * D;      // packed weights (ushort)
constexpr size_t ZERO_FLOATS = SIGN_OFF;

constexpr size_t P_SEC3 = 30ull * 20 * 64 * 8;
constexpr size_t P_SEC2 = 20ull * 20 * 64 * 8;
constexpr size_t P_SEC1 = 10ull * 20 * 64 * 8;

__device__ inline unsigned short f2bf(float f) {     // fp32 -> bf16 RNE
    unsigned int u = __float_as_uint(f);
    return (unsigned short)((u + 0x7fffu + ((u >> 16) & 1u)) >> 16);
}

__global__ void fill_sign_k(float* sign) {
    int i = blockIdx.x * blockDim.x + threadIdx.x;
    if (i < N_EDGES) sign[i] = 1.0f;
}

__global__ void scatter_sign_k(const int* __restrict__ ase, float* sign) {
    int i = blockIdx.x * blockDim.x + threadIdx.x;
    if (i < N_EDGES / 2) sign[ase[i]] = -1.0f;
}

// x[r][d0..d0+3] = sum_t emb[tok[r][t]][d0..d0+3]   (float4)
__global__ void embsum4_k(const int* __restrict__ tok, const float* __restrict__ emb,
                          float* out, int nrows) {
    int idx = blockIdx.x * blockDim.x + threadIdx.x;
    int total = nrows * 75;
    if (idx >= total) return;
    int r = idx / 75;
    int q = (idx - r * 75) * 4;
    int4 t = *(const int4*)(tok + (size_t)r * 4);
    float4 a = *(const float4*)(emb + (size_t)t.x * D + q);
    float4 b = *(const float4*)(emb + (size_t)t.y * D + q);
    float4 c = *(const float4*)(emb + (size_t)t.z * D + q);
    float4 d = *(const float4*)(emb + (size_t)t.w * D + q);
    float4 o;
    o.x = a.x + b.x + c.x + d.x; o.y = a.y + b.y + c.y + d.y;
    o.z = a.z + b.z + c.z + d.z; o.w = a.w + b.w + c.w + d.w;
    *(float4*)(out + (size_t)r * D + q) = o;
}

__global__ void count_col_k(const int* __restrict__ coli, float* cnt) {
    int i = blockIdx.x * blockDim.x + threadIdx.x;
    if (i < N_EDGES) atomicAdd(&cnt[coli[i]], 1.0f);
}

// Pack W [secs*300][300] fp32 -> fragment-major bf16 [kt][nt(20)][lane(64)][8].
// Fragment: lane holds B[k = kt*32 + (lane>>4)*8 + j][col = nt*16 + (lane&15)].
__global__ void pack_w_k(const float* __restrict__ W, unsigned short* __restrict__ out,
                         int secs) {
    int idx = blockIdx.x * blockDim.x + threadIdx.x;
    int total = secs * 12800;
    if (idx >= total) return;
    int lane = idx & 63;
    int nt = (idx >> 6) % 20;
    int kt = idx / 1280;
    int col = nt * 16 + (lane & 15);
    int kg = (lane >> 4) * 8;
#pragma unroll
    for (int j = 0; j < 8; ++j) {
        int p = kt * 32 + kg + j;
        int sec = p / 320;
        int kk = p - sec * 320;
        float w = 0.f;
        if (kk < 300 && col < 300) w = W[(size_t)(sec * 300 + kk) * 300 + col];
        out[(size_t)idx * 8 + j] = f2bf(w);
    }
}

// Fused 2-layer MLP on MFMA, issue-early prefetch staging. SECS = Fin/300.
// MODE 0: A = [x[row], x[col], ea(e) computed from emb]  -> store outp
// MODE 1: A = [x[row], edge_enc[e]]                      -> atomicAdd outp[col[e]]
// MODE 2: A = [x[n], agg[n]/cnt[n]]                      -> store outp + fused graph stats
template <int SECS, int MODE, bool SCATTER>
__global__ __launch_bounds__(256, (MODE == 0) ? 2 : 3) void mlp_mfma_k(
        const float* __restrict__ x, const float* __restrict__ aux,
        const int* __restrict__ rowi, const int* __restrict__ coli,
        const float* __restrict__ cnt, const float* __restrict__ sign,
        const int* __restrict__ eatok, const float* __restrict__ emb,
        const unsigned short* __restrict__ W1p, const float* __restrict__ b1,
        const unsigned short* __restrict__ W2p, const float* __restrict__ b2,
        float* outp, const int* __restrict__ batch,
        float* gsum, float* gsq, float* gcnt, int nrows)
{
    constexpr int NCHUNK = SECS * 5;
    // union: layer-1 staging Abuf [buf:8192][hl:4096][idx] ushorts (16384 total)
    //        layer-2 hidden Hs, fragment-major (20480 ushorts) — used after layer 1
    __shared__ __align__(16) unsigned short SM[20480];
    __shared__ int Cidx[64];
    __shared__ float RS[64], RQ[64];

    const int tid  = threadIdx.x;
    const int wave = tid >> 6;
    const int lane = tid & 63;
    const int r0   = blockIdx.x * 64;

    // staging identity: row sm, 16-float run at sko within 64-wide chunk
    const int sm  = tid >> 2;
    const int sko = (tid & 3) << 4;
    const int sbase = (((sko >> 5) * 4 + (sm >> 4)) * 64 + (sm & 15) + ((sko & 31) >> 3) * 16) * 8;
    int se = r0 + sm; if (se >= nrows) se = nrows - 1;

    if (tid < 64) {
        if constexpr (SCATTER) {
            int e = r0 + tid; if (e >= nrows) e = nrows - 1;
            Cidx[tid] = coli[e];
        }
        RS[tid] = 0.f; RQ[tid] = 0.f;
    }

    // per-thread staging bases
    const float* sb0; const float* sb1;
    const float *et0, *et1, *et2, *et3;
    float sgn = 1.f, icnt = 1.f;
    if constexpr (MODE == 0) {
        sb0 = x + (size_t)rowi[se] * D;
        sb1 = x + (size_t)coli[se] * D;
        int4 tk = *(const int4*)(eatok + (size_t)se * 4);
        et0 = emb + (size_t)tk.x * D; et1 = emb + (size_t)tk.y * D;
        et2 = emb + (size_t)tk.z * D; et3 = emb + (size_t)tk.w * D;
        sgn = sign[se];
    } else if constexpr (MODE == 1) {
        sb0 = x + (size_t)rowi[se] * D;
        sb1 = aux + (size_t)se * D;
    } else {
        sb0 = x + (size_t)se * D;
        sb1 = aux + (size_t)se * D;
        icnt = 1.0f / fmaxf(cnt[se], 1.0f);
    }

    float4 G[(MODE == 0) ? 16 : 4];
    float  f[16];

    auto issuef = [&](int c) {
        int s = c / 5;
        int kk0 = (c - s * 5) * 64 + sko;
        if constexpr (MODE == 0) {
            if (s == 2) {
#pragma unroll
                for (int q = 0; q < 4; ++q) {
                    int kk = kk0 + q * 4;
                    bool ok = (kk + 4 <= 300);
                    G[q]      = ok ? *(const float4*)(et0 + kk) : make_float4(0.f, 0.f, 0.f, 0.f);
                    G[4 + q]  = ok ? *(const float4*)(et1 + kk) : make_float4(0.f, 0.f, 0.f, 0.f);
                    G[8 + q]  = ok ? *(const float4*)(et2 + kk) : make_float4(0.f, 0.f, 0.f, 0.f);
                    G[12 + q] = ok ? *(const float4*)(et3 + kk) : make_float4(0.f, 0.f, 0.f, 0.f);
                }
                return;
            }
        }
        const float* b = (s == 0) ? sb0 : sb1;
#pragma unroll
        for (int q = 0; q < 4; ++q) {
            int kk = kk0 + q * 4;
            G[q] = (kk + 4 <= 300) ? *(const float4*)(b + kk) : make_float4(0.f, 0.f, 0.f, 0.f);
        }
    };

    auto finishf = [&](int c) {
        int s = c / 5;
#pragma unroll
        for (int q = 0; q < 4; ++q) {
            float4 v = G[q];
            if constexpr (MODE == 0) {
                if (s == 2) {
                    float4 t1 = G[4 + q], t2 = G[8 + q], t3 = G[12 + q];
                    v.x = sgn * (v.x + t1.x + t2.x + t3.x);
                    v.y = sgn * (v.y + t1.y + t2.y + t3.y);
                    v.z = sgn * (v.z + t1.z + t2.z + t3.z);
                    v.w = sgn * (v.w + t1.w + t2.w + t3.w);
                }
            }
            if constexpr (MODE == 2) {
                if (s == 1) { v.x *= icnt; v.y *= icnt; v.z *= icnt; v.w *= icnt; }
            }
            f[q * 4 + 0] = v.x; f[q * 4 + 1] = v.y; f[q * 4 + 2] = v.z; f[q * 4 + 3] = v.w;
        }
    };

    // hi = trunc_bf16(f) (perm pair-pack), lo = bf16(f - hi) — exact split
    auto convertf = [&](int buf) {
        unsigned int uh[8], ul[8];
#pragma unroll
        for (int j = 0; j < 8; ++j) {
            float a = f[2 * j], b = f[2 * j + 1];
            unsigned int ua = __float_as_uint(a), ub = __float_as_uint(b);
            uh[j] = __builtin_amdgcn_perm(ub, ua, 0x07060302u);
            float la = a - __uint_as_float(ua & 0xffff0000u);
            float lb = b - __uint_as_float(ub & 0xffff0000u);
            ul[j] = __builtin_amdgcn_perm(__float_as_uint(lb), __float_as_uint(la), 0x07060302u);
        }
        int b0 = buf * 8192;
        *(uint4*)&SM[b0 + sbase]              = make_uint4(uh[0], uh[1], uh[2], uh[3]);
        *(uint4*)&SM[b0 + sbase + 128]        = make_uint4(uh[4], uh[5], uh[6], uh[7]);
        *(uint4*)&SM[b0 + 4096 + sbase]       = make_uint4(ul[0], ul[1], ul[2], ul[3]);
        *(uint4*)&SM[b0 + 4096 + sbase + 128] = make_uint4(ul[4], ul[5], ul[6], ul[7]);
    };

    fx4 acc[4][5];
#pragma unroll
    for (int a = 0; a < 4; ++a)
#pragma unroll
        for (int b = 0; b < 5; ++b) acc[a][b] = fx4{0.f, 0.f, 0.f, 0.f};

    // prologue: stage chunk 0
    issuef(0);
    finishf(0);
    convertf(0);
    __syncthreads();

    // ---------------- layer 1 ----------------
    for (int c = 0; c < NCHUNK; ++c) {
        const int cur = c & 1;
        if (c + 1 < NCHUNK) issuef(c + 1);   // loads in flight across the MFMA phase
#pragma unroll
        for (int kt = 0; kt < 2; ++kt) {
            const int ktg = c * 2 + kt;
            bh8 bfr[5];
#pragma unroll
            for (int nt = 0; nt < 5; ++nt)
                bfr[nt] = *(const bh8*)(W1p + (((size_t)ktg * 20 + wave * 5 + nt) * 64 + lane) * 8);
#pragma unroll
            for (int mt = 0; mt < 4; ++mt) {
                bh8 ah = *(const bh8*)&SM[cur * 8192 + ((kt * 4 + mt) * 64 + lane) * 8];
                bh8 al = *(const bh8*)&SM[cur * 8192 + 4096 + ((kt * 4 + mt) * 64 + lane) * 8];
#pragma unroll
                for (int nt = 0; nt < 5; ++nt) {
                    acc[mt][nt] = __builtin_amdgcn_mfma_f32_16x16x32_bf16(ah, bfr[nt], acc[mt][nt], 0, 0, 0);
                    acc[mt][nt] = __builtin_amdgcn_mfma_f32_16x16x32_bf16(al, bfr[nt], acc[mt][nt], 0, 0, 0);
                }
            }
        }
        if (c + 1 < NCHUNK) {
            finishf(c + 1);       // loads landed during MFMA phase
            convertf(cur ^ 1);    // safe: last reader of buf cur^1 was MFMA(c-1), barrier-separated
        }
        __syncthreads();
    }

    // epilogue 1: Hs = bf16(relu(acc + b1)), fragment-major (reuses SM — Abuf now dead)
    const int rg = (lane >> 4) * 4;
    // zero pad cols [300,320)
    for (int i = tid; i < 64 * 20; i += 256) {
        int row = i / 20, h = 300 + (i % 20);
        SM[((h >> 5) * 4 + ((h >> 3) & 3)) * 512 + row * 8 + (h & 7)] = 0;
    }
    {
#pragma unroll
        for (int nt = 0; nt < 5; ++nt) {
            int col = (wave * 5 + nt) * 16 + (lane & 15);
            if (col < 300) {
                float bb = b1[col];
                int hoff = ((col >> 5) * 4 + ((col >> 3) & 3)) * 512 + (col & 7);
#pragma unroll
                for (int mt = 0; mt < 4; ++mt)
#pragma unroll
                    for (int r = 0; r < 4; ++r) {
                        float v = fmaxf(acc[mt][nt][r] + bb, 0.f);
                        SM[hoff + (mt * 16 + rg + r) * 8] = f2bf(v);
                    }
            }
        }
    }
    __syncthreads();

    // ---------------- layer 2 (no barriers) ----------------
#pragma unroll
    for (int a = 0; a < 4; ++a)
#pragma unroll
        for (int b = 0; b < 5; ++b) acc[a][b] = fx4{0.f, 0.f, 0.f, 0.f};

    for (int kt = 0; kt < 10; ++kt) {
        bh8 bfr[5];
#pragma unroll
        for (int nt = 0; nt < 5; ++nt)
            bfr[nt] = *(const bh8*)(W2p + (((size_t)kt * 20 + wave * 5 + nt) * 64 + lane) * 8);
#pragma unroll
        for (int mt = 0; mt < 4; ++mt) {
            bh8 ah = *(const bh8*)&SM[((kt * 4 + (lane >> 4)) * 64 + mt * 16 + (lane & 15)) * 8];
#pragma unroll
            for (int nt = 0; nt < 5; ++nt)
                acc[mt][nt] = __builtin_amdgcn_mfma_f32_16x16x32_bf16(ah, bfr[nt], acc[mt][nt], 0, 0, 0);
        }
    }

    // epilogue 2: store / scatter (+ fused graph stats for MODE 2)
    float s1a[16], s2a[16];
    if constexpr (MODE == 2) {
#pragma unroll
        for (int i = 0; i < 16; ++i) { s1a[i] = 0.f; s2a[i] = 0.f; }
    }
#pragma unroll
    for (int nt = 0; nt < 5; ++nt) {
        int col = (wave * 5 + nt) * 16 + (lane & 15);
        if (col >= 300) continue;
        float bb = b2[col];
#pragma unroll
        for (int mt = 0; mt < 4; ++mt)
#pragma unroll
            for (int r = 0; r < 4; ++r) {
                int m = mt * 16 + rg + r;
                int e = r0 + m;
                if (e >= nrows) continue;
                float v = acc[mt][nt][r] + bb;
                if constexpr (SCATTER) atomicAdd(&outp[(size_t)Cidx[m] * D + col], v);
                else                   outp[(size_t)e * D + col] = v;
                if constexpr (MODE == 2) { s1a[mt * 4 + r] += v; s2a[mt * 4 + r] += v * v; }
            }
    }

    if constexpr (MODE == 2) {
#pragma unroll
        for (int i = 0; i < 16; ++i) {
            float s = s1a[i], q = s2a[i];
            s += __shfl_xor(s, 1, 64); q += __shfl_xor(q, 1, 64);
            s += __shfl_xor(s, 2, 64); q += __shfl_xor(q, 2, 64);
            s += __shfl_xor(s, 4, 64); q += __shfl_xor(q, 4, 64);
            s += __shfl_xor(s, 8, 64); q += __shfl_xor(q, 8, 64);
            if ((lane & 15) == 0) {
                int row = (i >> 2) * 16 + rg + (i & 3);
                atomicAdd(&RS[row], s);
                atomicAdd(&RQ[row], q);
            }
        }
        __syncthreads();
        if (tid < 64) {
            int e = r0 + tid;
            if (e < nrows) {
                int g = batch[e];
                atomicAdd(&gsum[g], RS[tid]);
                atomicAdd(&gsq[g],  RQ[tid]);
                atomicAdd(&gcnt[g], 1.0f);
            }
        }
    }
}

__global__ void graph_norm4_k(float* xe, const int* __restrict__ batch,
                              const float* __restrict__ gsum, const float* __restrict__ gsq,
                              const float* __restrict__ gcnt,
                              const float* __restrict__ lnw, const float* __restrict__ lnb) {
    int idx = blockIdx.x * blockDim.x + threadIdx.x;
    if (idx >= N_NODES * 75) return;
    int n = idx / 75;
    int d = (idx - n * 75) * 4;
    int g = batch[n];
    float denom = fmaxf(gcnt[g] * (float)D, 1.0f);
    float mean = gsum[g] / denom;
    float var  = gsq[g] / denom - mean * mean;
    float r = rsqrtf(var + EPSV);
    float4 v  = *(const float4*)(xe + (size_t)n * D + d);
    float4 w  = *(const float4*)(lnw + d);
    float4 bb = *(const float4*)(lnb + d);
    v.x = (v.x - mean) * r * w.x + bb.x;
    v.y = (v.y - mean) * r * w.y + bb.y;
    v.z = (v.z - mean) * r * w.z + bb.z;
    v.w = (v.w - mean) * r * w.w + bb.w;
    *(float4*)(xe + (size_t)n * D + d) = v;
}

extern "C" void kernel_launch(void* const* d_in, const int* in_sizes, int n_in,
                              void* d_out, int out_size, void* d_ws, size_t ws_size,
                              hipStream_t stream) {
    const int*   x_tok  = (const int*)d_in[0];
    const int*   ea_tok = (const int*)d_in[1];
    const int*   eidx   = (const int*)d_in[2];
    const int*   ase    = (const int*)d_in[3];
    const int*   batch  = (const int*)d_in[4];
    const float* emb    = (const float*)d_in[5];
    const float* ew1  = (const float*)d_in[6];
    const float* eb1  = (const float*)d_in[7];
    const float* ew2  = (const float*)d_in[8];
    const float* eb2  = (const float*)d_in[9];
    const float* n1w1 = (const float*)d_in[10];
    const float* n1b1 = (const float*)d_in[11];
    const float* n1w2 = (const float*)d_in[12];
    const float* n1b2 = (const float*)d_in[13];
    const float* n2w1 = (const float*)d_in[14];
    const float* n2b1 = (const float*)d_in[15];
    const float* n2w2 = (const float*)d_in[16];
    const float* n2b2 = (const float*)d_in[17];
    const float* lnw  = (const float*)d_in[18];
    const float* lnb  = (const float*)d_in[19];

    const int* rowi = eidx;
    const int* coli = eidx + N_EDGES;

    float* out  = (float*)d_out;
    float* xout = out;
    float* eenc = out + (size_t)N_NODES * D;

    float* ws   = (float*)d_ws;
    float* agg  = ws + AGG_OFF;
    float* cnt  = ws + CNT_OFF;
    float* gsum = ws + GSUM_OFF;
    float* gsq  = ws + GSQ_OFF;
    float* gcnt = ws + GCNT_OFF;
    float* sign = ws + SIGN_OFF;
    float* x    = ws + X_OFF;

    unsigned short* ew1p  = (unsigned short*)(ws + PACK_OFF);
    unsigned short* ew2p  = ew1p  + P_SEC3;
    unsigned short* n1w1p = ew2p  + P_SEC1;
    unsigned short* n1w2p = n1w1p + P_SEC2;
    unsigned short* n2w1p = n1w2p + P_SEC1;
    unsigned short* n2w2p = n2w1p + P_SEC2;

    // 0. pack weights
    pack_w_k<<<(3 * 12800 + 255) / 256, 256, 0, stream>>>(ew1,  ew1p,  3);
    pack_w_k<<<(1 * 12800 + 255) / 256, 256, 0, stream>>>(ew2,  ew2p,  1);
    pack_w_k<<<(2 * 12800 + 255) / 256, 256, 0, stream>>>(n1w1, n1w1p, 2);
    pack_w_k<<<(1 * 12800 + 255) / 256, 256, 0, stream>>>(n1w2, n1w2p, 1);
    pack_w_k<<<(2 * 12800 + 255) / 256, 256, 0, stream>>>(n2w1, n2w1p, 2);
    pack_w_k<<<(1 * 12800 + 255) / 256, 256, 0, stream>>>(n2w2, n2w2p, 1);

    // 1. zero accumulators
    hipMemsetAsync(ws, 0, ZERO_FLOATS * sizeof(float), stream);

    // 2. sign
    fill_sign_k<<<(N_EDGES + 255) / 256, 256, 0, stream>>>(sign);
    scatter_sign_k<<<(N_EDGES / 2 + 255) / 256, 256, 0, stream>>>(ase, sign);

    // 3. node embedding sums (edge ea is fused into the edge MLP)
    embsum4_k<<<(N_NODES * 75 + 255) / 256, 256, 0, stream>>>(x_tok, emb, x, N_NODES);

    // 4. edge MLP (ea computed on the fly) -> edge_enc
    mlp_mfma_k<3, 0, false><<<N_EDGES / 64, 256, 0, stream>>>(
        x, nullptr, rowi, coli, nullptr, sign, ea_tok, emb,
        ew1p, eb1, ew2p, eb2, eenc, nullptr, nullptr, nullptr, nullptr, N_EDGES);

    // 5. in-degree counts
    count_col_k<<<(N_EDGES + 255) / 256, 256, 0, stream>>>(coli, cnt);

    // 6. node MLP1 -> scatter-add into agg
    mlp_mfma_k<2, 1, true><<<N_EDGES / 64, 256, 0, stream>>>(
        x, eenc, rowi, coli, nullptr, nullptr, nullptr, nullptr,
        n1w1p, n1b1, n1w2p, n1b2, agg, nullptr, nullptr, nullptr, nullptr, N_EDGES);

    // 7. node MLP2 (agg/cnt folded) -> x_enc + fused graph stats
    mlp_mfma_k<2, 2, false><<<(N_NODES + 63) / 64, 256, 0, stream>>>(
        x, agg, nullptr, nullptr, cnt, nullptr, nullptr, nullptr,
        n2w1p, n2b1, n2w2p, n2b2, xout, batch, gsum, gsq, gcnt, N_NODES);

    // 8. graph layernorm
    graph_norm4_k<<<(N_NODES * 75 + 255) / 256, 256, 0, stream>>>(
        xout, batch, gsum, gsq, gcnt, lnw, lnb);
}